// Round 4
// baseline (518.225 us; speedup 1.0000x reference)
//
#include <hip/hip_runtime.h>

// TemporalAttentionCausal, fused single-pass kernel, v2.
// out[bl,t,c] = h + cumsum_t(e*h)/(cumsum_t(e)+eps), e = exp(dot(h[bl,t,:],w)+b0).
// Max-subtraction dropped (verified passing, absmax 0.0078).
//
// One block per (bl, 64-t chunk); chunk h staged in LDS (64 KiB) so h is read
// from HBM exactly once and out is written straight from LDS.
// Cross-chunk prefix via a CHAINED per-bl counter (v1's 15-flag all-wave spin
// was the failure: ~30K lanes hammering agent-scope lines -> 412us, VALU 1.8%).
// v2: chunk j's publisher stores its partials, then ONE lane polls
// done_cnt[bl]==j with s_sleep backoff and release-stores j+1. Counter >= j
// transitively (release chain) makes all predecessor partials visible.
// Deadlock-free: dense ticket => a block waits only on smaller tickets.

constexpr int Tn = 1024, Hn = 256;
constexpr int BL   = 128;           // B*L
constexpr int CT   = 64;            // t per chunk
constexpr int NC   = Tn / CT;       // 16 chunks per bl
constexpr int F4   = Hn / 4;        // 64 float4 per row
constexpr int NBLK = BL * NC;       // 2048 blocks

__global__ __launch_bounds__(256) void k_fused(
    const float* __restrict__ h, const float* __restrict__ w,
    const float* __restrict__ bias, float* __restrict__ out,
    int* __restrict__ ticket, int* __restrict__ done_cnt,
    float* __restrict__ P, float* __restrict__ Se)
{
    const int tid  = threadIdx.x;
    const int wv   = tid >> 6, lane = tid & 63;
    const int g    = lane >> 4, sub = lane & 15;   // 16-lane groups

    __shared__ float4 hbuf[CT * F4];    // 64 KiB staged chunk
    __shared__ float  e_s[CT], cums[CT];
    __shared__ float4 PW[4][F4];        // per-wave channel partials
    __shared__ float  esw[4];
    __shared__ int    vb_s;

    if (tid == 0) vb_s = atomicAdd(ticket, 1);
    __syncthreads();
    const int vbid = vb_s;
    const int j  = vbid >> 7;           // chunk 0..15
    const int bl = vbid & (BL - 1);

    const float b0 = bias[0];
    const float4* wp = reinterpret_cast<const float4*>(w);
    float4 w4[4];
    #pragma unroll
    for (int q = 0; q < 4; ++q) w4[q] = wp[sub + 16 * q];

    const size_t base4 = ((size_t)bl * Tn + (size_t)j * CT) * F4;
    const float4* __restrict__ h4 = reinterpret_cast<const float4*>(h);

    // ---- phase A: stage h -> LDS, e, per-wave partials. 16 rows/wave. ----
    const int r0 = wv * 16;
    float4 acc[4] = {{0,0,0,0},{0,0,0,0},{0,0,0,0},{0,0,0,0}};
    float esum = 0.f;
    #pragma unroll
    for (int i = 0; i < 4; ++i) {
        const int r = r0 + i * 4 + g;   // group g owns row r
        float4 x[4];
        #pragma unroll
        for (int q = 0; q < 4; ++q) x[q] = h4[base4 + (size_t)r * F4 + sub + 16 * q];
        float p = 0.f;
        #pragma unroll
        for (int q = 0; q < 4; ++q) {
            p = fmaf(x[q].x, w4[q].x, p); p = fmaf(x[q].y, w4[q].y, p);
            p = fmaf(x[q].z, w4[q].z, p); p = fmaf(x[q].w, w4[q].w, p);
        }
        p += __shfl_xor(p, 1); p += __shfl_xor(p, 2);
        p += __shfl_xor(p, 4); p += __shfl_xor(p, 8);
        const float e = __expf(p + b0);
        esum += e;
        #pragma unroll
        for (int q = 0; q < 4; ++q) {
            acc[q].x = fmaf(e, x[q].x, acc[q].x); acc[q].y = fmaf(e, x[q].y, acc[q].y);
            acc[q].z = fmaf(e, x[q].z, acc[q].z); acc[q].w = fmaf(e, x[q].w, acc[q].w);
            hbuf[r * F4 + sub + 16 * q] = x[q];
        }
        if (sub == 0) e_s[r] = e;
    }
    #pragma unroll
    for (int q = 0; q < 4; ++q) {
        acc[q].x += __shfl_xor(acc[q].x, 16); acc[q].x += __shfl_xor(acc[q].x, 32);
        acc[q].y += __shfl_xor(acc[q].y, 16); acc[q].y += __shfl_xor(acc[q].y, 32);
        acc[q].z += __shfl_xor(acc[q].z, 16); acc[q].z += __shfl_xor(acc[q].z, 32);
        acc[q].w += __shfl_xor(acc[q].w, 16); acc[q].w += __shfl_xor(acc[q].w, 32);
    }
    esum += __shfl_xor(esum, 16); esum += __shfl_xor(esum, 32);
    if (lane < 16) {
        PW[wv][sub]      = acc[0];
        PW[wv][sub + 16] = acc[1];
        PW[wv][sub + 32] = acc[2];
        PW[wv][sub + 48] = acc[3];
    }
    if (lane == 0) esw[wv] = esum;
    __syncthreads();    // hbuf, e_s, PW, esw valid

    // ---- wave 0: local inclusive e-scan; wave 1: publish + chain-advance ----
    if (wv == 0) {
        float c = e_s[lane];
        #pragma unroll
        for (int off = 1; off < 64; off <<= 1) {
            const float n = __shfl_up(c, off);
            if (lane >= off) c += n;
        }
        cums[lane] = c;
    } else if (wv == 1) {
        float4 p4 = PW[0][lane];
        const float4 q1 = PW[1][lane], q2 = PW[2][lane], q3 = PW[3][lane];
        p4.x += q1.x + q2.x + q3.x;  p4.y += q1.y + q2.y + q3.y;
        p4.z += q1.z + q2.z + q3.z;  p4.w += q1.w + q2.w + q3.w;
        const int slot = (bl << 4) + j;
        reinterpret_cast<float4*>(P + (size_t)slot * Hn)[lane] = p4;
        if (lane == 0) Se[slot] = (esw[0] + esw[1]) + (esw[2] + esw[3]);
        __threadfence();
        if (lane == 0) {
            // chain: wait for predecessor count, then advance. ONE poller,
            // coarse backoff -> no coherent-load storm (v1's killer).
            while (__hip_atomic_load(&done_cnt[bl], __ATOMIC_ACQUIRE,
                                     __HIP_MEMORY_SCOPE_AGENT) < j) {
                __builtin_amdgcn_s_sleep(8);
            }
            __hip_atomic_store(&done_cnt[bl], j + 1, __ATOMIC_RELEASE,
                               __HIP_MEMORY_SCOPE_AGENT);
        }
    }
    __syncthreads();    // cums ready; all predecessor partials visible

    // ---- offsets: sum of <=15 predecessor partial rows (L2-hot) ----
    float  seo  = 0.f;
    float4 off4 = make_float4(0.f, 0.f, 0.f, 0.f);
    for (int jj = 0; jj < j; ++jj) {
        const int slot = (bl << 4) + jj;
        const float* pp = P + (size_t)slot * Hn + lane * 4;
        off4.x += __hip_atomic_load(pp + 0, __ATOMIC_RELAXED, __HIP_MEMORY_SCOPE_AGENT);
        off4.y += __hip_atomic_load(pp + 1, __ATOMIC_RELAXED, __HIP_MEMORY_SCOPE_AGENT);
        off4.z += __hip_atomic_load(pp + 2, __ATOMIC_RELAXED, __HIP_MEMORY_SCOPE_AGENT);
        off4.w += __hip_atomic_load(pp + 3, __ATOMIC_RELAXED, __HIP_MEMORY_SCOPE_AGENT);
        seo    += __hip_atomic_load(&Se[slot], __ATOMIC_RELAXED, __HIP_MEMORY_SCOPE_AGENT);
    }
    #pragma unroll
    for (int ww = 0; ww < 3; ++ww) {
        if (ww < wv) {
            const float4 q = PW[ww][lane];
            off4.x += q.x; off4.y += q.y; off4.z += q.z; off4.w += q.w;
        }
    }

    // ---- output: running per-channel cumsum straight from LDS ----
    float4 a = off4;
    float4* __restrict__ o4 = reinterpret_cast<float4*>(out);
    #pragma unroll
    for (int u = 0; u < 16; ++u) {
        const int r = r0 + u;
        const float4 x = hbuf[r * F4 + lane];
        const float  e = e_s[r];
        a.x = fmaf(e, x.x, a.x); a.y = fmaf(e, x.y, a.y);
        a.z = fmaf(e, x.z, a.z); a.w = fmaf(e, x.w, a.w);
        const float s = 1.0f / (seo + cums[r] + 1e-12f);
        float4 o;
        o.x = fmaf(a.x, s, x.x); o.y = fmaf(a.y, s, x.y);
        o.z = fmaf(a.z, s, x.z); o.w = fmaf(a.w, s, x.w);
        o4[base4 + (size_t)r * F4 + lane] = o;
    }
}

extern "C" void kernel_launch(void* const* d_in, const int* in_sizes, int n_in,
                              void* d_out, int out_size, void* d_ws, size_t ws_size,
                              hipStream_t stream) {
    const float* h = (const float*)d_in[0];
    const float* w = (const float*)d_in[1];
    const float* b = (const float*)d_in[2];
    float* out = (float*)d_out;

    char* ws = (char*)d_ws;
    int*   ticket   = (int*)ws;                         // 1 int
    int*   done_cnt = (int*)(ws + 128);                 // BL ints
    float* P        = (float*)(ws + 4096);              // NBLK*Hn floats (2 MB)
    float* Se       = (float*)(ws + 4096 + (size_t)NBLK * Hn * 4);  // NBLK floats

    // ticket + counters are poisoned between iterations -> re-zero (1 KB).
    hipMemsetAsync(d_ws, 0, 1024, stream);
    k_fused<<<NBLK, 256, 0, stream>>>(h, w, b, out, ticket, done_cnt, P, Se);
}

// Round 8
// 320.496 us; speedup vs baseline: 1.6169x; 1.6169x over previous
//
#include <hip/hip_runtime.h>
#include <hip/hip_cooperative_groups.h>

namespace cg = cooperative_groups;

// TemporalAttentionCausal: out = h + cumsum_t(e*h) / (cumsum_t(e) + eps),
// e = exp(dot(h[bl,t,:], w) + b0). Max-subtraction dropped (verified passing,
// absmax 0.0078).
//
// Cooperative kernel (512 blocks, 2 items/block/phase) with HOST-SIDE FALLBACK
// to the proven round-2 two-kernel path if the cooperative launch is rejected.
// Round-6's 1024-block coop version returned all zeros (absmax == max|ref|)
// => launch rejected (1024 = exactly 256CU x 4/CU, zero margin; or CG not
// supported under graph capture). 512 blocks @ __launch_bounds__(256,2) has
// 2x margin; the fallback makes launch rejection non-fatal and A/B-visible
// via rocprof kernel names.

constexpr int Tn = 1024, Hn = 256;
constexpr int BL  = 128;          // B*L
constexpr int NCH = 8;            // work items per bl
constexpr int F4  = Hn / 4;       // 64 float4 per row
constexpr int NW  = Tn / 32;      // 32 windows of 32 t per bl
constexpr int NBLK = 512;         // coop grid: 2x co-residency margin
constexpr int REP  = BL * NCH / NBLK;   // 2 items per block per phase

// ---------------- phase bodies (shared by coop + fallback) ----------------
__device__ __forceinline__ void phase1_body(int vb, int wave, int lane,
                                            int g, int sub, float b0,
                                            const float4* __restrict__ wp4,
                                            const float* __restrict__ h,
                                            float* __restrict__ ebuf,
                                            float* __restrict__ P32,
                                            float* __restrict__ Se32) {
    const int j = vb & 7, bl = vb >> 3;
    const int W = j * 4 + wave;
    const int t0w = W * 32;
    const float4* hp = reinterpret_cast<const float4*>(h) + (size_t)bl * Tn * F4;

    float4 acc[4] = {{0,0,0,0},{0,0,0,0},{0,0,0,0},{0,0,0,0}};
    float esum = 0.f;
    #pragma unroll
    for (int i = 0; i < 8; ++i) {
        const int t = t0w + i * 4 + g;
        float4 x[4];
        #pragma unroll
        for (int q = 0; q < 4; ++q) x[q] = hp[(size_t)t * F4 + sub + 16 * q];
        float p = 0.f;
        #pragma unroll
        for (int q = 0; q < 4; ++q) {
            p = fmaf(x[q].x, wp4[q].x, p);
            p = fmaf(x[q].y, wp4[q].y, p);
            p = fmaf(x[q].z, wp4[q].z, p);
            p = fmaf(x[q].w, wp4[q].w, p);
        }
        p += __shfl_xor(p, 1);
        p += __shfl_xor(p, 2);
        p += __shfl_xor(p, 4);
        p += __shfl_xor(p, 8);
        const float e = __expf(p + b0);
        esum += e;
        #pragma unroll
        for (int q = 0; q < 4; ++q) {
            acc[q].x = fmaf(e, x[q].x, acc[q].x);
            acc[q].y = fmaf(e, x[q].y, acc[q].y);
            acc[q].z = fmaf(e, x[q].z, acc[q].z);
            acc[q].w = fmaf(e, x[q].w, acc[q].w);
        }
        if (sub == 0) ebuf[bl * Tn + t] = e;
    }
    #pragma unroll
    for (int q = 0; q < 4; ++q) {
        acc[q].x += __shfl_xor(acc[q].x, 16); acc[q].x += __shfl_xor(acc[q].x, 32);
        acc[q].y += __shfl_xor(acc[q].y, 16); acc[q].y += __shfl_xor(acc[q].y, 32);
        acc[q].z += __shfl_xor(acc[q].z, 16); acc[q].z += __shfl_xor(acc[q].z, 32);
        acc[q].w += __shfl_xor(acc[q].w, 16); acc[q].w += __shfl_xor(acc[q].w, 32);
    }
    esum += __shfl_xor(esum, 16);  esum += __shfl_xor(esum, 32);

    if (lane < 16) {
        float4* pp = reinterpret_cast<float4*>(P32) + ((size_t)bl * NW + W) * F4;
        pp[sub]      = acc[0];
        pp[sub + 16] = acc[1];
        pp[sub + 32] = acc[2];
        pp[sub + 48] = acc[3];
    }
    if (lane == 0) Se32[bl * NW + W] = esum;
}

__device__ __forceinline__ void phase2_body(int vb, int wave, int lane,
                                            const float* __restrict__ h,
                                            const float* __restrict__ ebuf,
                                            const float* __restrict__ P32,
                                            const float* __restrict__ Se32,
                                            float* __restrict__ out) {
    const int j = vb & 7, bl = vb >> 3;
    const int W = j * 4 + wave;
    const int t0w = W * 32;

    const float4* Pp = reinterpret_cast<const float4*>(P32) + (size_t)bl * NW * F4;
    float4 off4 = make_float4(0.f, 0.f, 0.f, 0.f);
    for (int q = 0; q < W; ++q) {
        const float4 v = Pp[q * F4 + lane];
        off4.x += v.x; off4.y += v.y; off4.z += v.z; off4.w += v.w;
    }
    float seo = 0.f;
    if (lane < W) seo = Se32[bl * NW + lane];
    seo += __shfl_xor(seo, 1); seo += __shfl_xor(seo, 2);
    seo += __shfl_xor(seo, 4); seo += __shfl_xor(seo, 8);
    seo += __shfl_xor(seo, 16);
    seo = __shfl(seo, 0);

    float ev = 0.f;
    if (lane < 32) ev = ebuf[bl * Tn + t0w + lane];
    float sc = ev;
    #pragma unroll
    for (int off = 1; off < 32; off <<= 1) {
        const float n = __shfl_up(sc, off);
        if (lane >= off) sc += n;
    }
    const float sdv = 1.0f / (seo + sc + 1e-12f);   // valid on lanes < 32

    const float4* hp = reinterpret_cast<const float4*>(h)
                       + ((size_t)bl * Tn + t0w) * F4 + lane;
    float4* op = reinterpret_cast<float4*>(out)
                 + ((size_t)bl * Tn + t0w) * F4 + lane;

    float4 a = off4;
    #pragma unroll
    for (int i = 0; i < 32; i += 8) {
        float4 x[8];
        #pragma unroll
        for (int u = 0; u < 8; ++u) x[u] = hp[(size_t)(i + u) * F4];
        #pragma unroll
        for (int u = 0; u < 8; ++u) {
            const float e = __shfl(ev,  i + u);
            const float s = __shfl(sdv, i + u);
            a.x = fmaf(e, x[u].x, a.x); a.y = fmaf(e, x[u].y, a.y);
            a.z = fmaf(e, x[u].z, a.z); a.w = fmaf(e, x[u].w, a.w);
            float4 o;
            o.x = fmaf(a.x, s, x[u].x); o.y = fmaf(a.y, s, x[u].y);
            o.z = fmaf(a.z, s, x[u].z); o.w = fmaf(a.w, s, x[u].w);
            op[(size_t)(i + u) * F4] = o;
        }
    }
}

// ---------------- cooperative single-kernel path ----------------
__global__ __launch_bounds__(256, 2) void k_coop(const float* __restrict__ h,
                                                 const float* __restrict__ w,
                                                 const float* __restrict__ bias,
                                                 float* __restrict__ ebuf,
                                                 float* __restrict__ P32,
                                                 float* __restrict__ Se32,
                                                 float* __restrict__ out) {
    const int wave = threadIdx.x >> 6, lane = threadIdx.x & 63;
    const int g = lane >> 4, sub = lane & 15;
    const float b0 = bias[0];
    const float4* wp = reinterpret_cast<const float4*>(w);
    float4 w4[4];
    #pragma unroll
    for (int q = 0; q < 4; ++q) w4[q] = wp[sub + 16 * q];

    #pragma unroll
    for (int rep = 0; rep < REP; ++rep)
        phase1_body(blockIdx.x + rep * NBLK, wave, lane, g, sub, b0, w4,
                    h, ebuf, P32, Se32);

    cg::this_grid().sync();

    #pragma unroll
    for (int rep = 0; rep < REP; ++rep)
        phase2_body(blockIdx.x + rep * NBLK, wave, lane,
                    h, ebuf, P32, Se32, out);
}

// ---------------- fallback two-kernel path (round-2, proven) ----------------
__global__ __launch_bounds__(256) void k_scores(const float* __restrict__ h,
                                                const float* __restrict__ w,
                                                const float* __restrict__ bias,
                                                float* __restrict__ ebuf,
                                                float* __restrict__ P32,
                                                float* __restrict__ Se32) {
    const int wave = threadIdx.x >> 6, lane = threadIdx.x & 63;
    const int g = lane >> 4, sub = lane & 15;
    const float b0 = bias[0];
    const float4* wp = reinterpret_cast<const float4*>(w);
    float4 w4[4];
    #pragma unroll
    for (int q = 0; q < 4; ++q) w4[q] = wp[sub + 16 * q];
    phase1_body(blockIdx.x, wave, lane, g, sub, b0, w4, h, ebuf, P32, Se32);
}

__global__ __launch_bounds__(256) void k_apply(const float* __restrict__ h,
                                               const float* __restrict__ ebuf,
                                               const float* __restrict__ P32,
                                               const float* __restrict__ Se32,
                                               float* __restrict__ out) {
    const int wave = threadIdx.x >> 6, lane = threadIdx.x & 63;
    phase2_body(blockIdx.x, wave, lane, h, ebuf, P32, Se32, out);
}

extern "C" void kernel_launch(void* const* d_in, const int* in_sizes, int n_in,
                              void* d_out, int out_size, void* d_ws, size_t ws_size,
                              hipStream_t stream) {
    const float* h = (const float*)d_in[0];
    const float* w = (const float*)d_in[1];
    const float* b = (const float*)d_in[2];
    float* out = (float*)d_out;

    float* ebuf = (float*)d_ws;                     // BL*Tn floats   (512 KB)
    float* P32  = ebuf + BL * Tn;                   // BL*NW*Hn floats (4 MB)
    float* Se32 = P32 + (size_t)BL * NW * Hn;       // BL*NW floats   (16 KB)

    void* args[] = {(void*)&h, (void*)&w, (void*)&b,
                    (void*)&ebuf, (void*)&P32, (void*)&Se32, (void*)&out};
    hipError_t err = hipLaunchCooperativeKernel(reinterpret_cast<void*>(k_coop),
                                                dim3(NBLK), dim3(256), args, 0,
                                                stream);
    if (err != hipSuccess) {
        (void)hipGetLastError();   // clear sticky error before fallback
        k_scores<<<BL * NCH, 256, 0, stream>>>(h, w, b, ebuf, P32, Se32);
        k_apply <<<BL * NCH, 256, 0, stream>>>(h, ebuf, P32, Se32, out);
    }
}